// Round 4
// baseline (111.845 us; speedup 1.0000x reference)
//
#include <hip/hip_runtime.h>

// C^4 for B independent 6x6 fp32 matrices — grid-stride pipelined version.
// Block = 256 threads, processes many 256-matrix chunks. Double-buffered LDS
// (2 x 36 KB), async global_load_lds staging with COUNTED vmcnt waits and raw
// s_barrier so the next chunk's loads stay in flight across the barrier
// (m201/m218 pattern; __syncthreads would drain vmcnt to 0 and expose HBM
// latency every chunk).
//
// vmcnt FIFO accounting per wave (all chunks full, 9 instrs per STAGE, 9 per
// gather-store):
//   iter 0:            [STAGE(0):9][STAGE(1):9]            -> wait vmcnt(9)
//   iter 1..n-2:       [STAGE(t):9][stores(t-1):9][STAGE(t+1):9] -> vmcnt(18)
//   iter n-1 (no pf):  [STAGE(n-1):9][stores(n-2):9]       -> vmcnt(9)
// The 128-matrix remainder (B % 256) is done register-direct by block 0's
// epilogue so every staged chunk is full (partial STAGE would break counts).

#define MPB 256   // matrices per chunk (= threads per block)
#define NB  512   // grid blocks = 2 resident per CU (LDS-limited)

#define GLOBAL_AS __attribute__((address_space(1)))
#define LDS_AS    __attribute__((address_space(3)))

#define WAITV0()  asm volatile("s_waitcnt vmcnt(0)" ::: "memory")
#define WAITV9()  asm volatile("s_waitcnt vmcnt(9)" ::: "memory")
#define WAITV18() asm volatile("s_waitcnt vmcnt(18)" ::: "memory")
#define WAITL()   asm volatile("s_waitcnt lgkmcnt(0)" ::: "memory")
#define BAR()     asm volatile("s_barrier" ::: "memory")

__device__ __forceinline__ void pow4_regs(float a[36])
{
    float b[36];
#pragma unroll
    for (int i = 0; i < 6; ++i)
#pragma unroll
        for (int j = 0; j < 6; ++j) {
            float s = a[i * 6 + 0] * a[0 * 6 + j];
#pragma unroll
            for (int k = 1; k < 6; ++k)
                s = fmaf(a[i * 6 + k], a[k * 6 + j], s);
            b[i * 6 + j] = s;
        }
#pragma unroll
    for (int i = 0; i < 6; ++i)
#pragma unroll
        for (int j = 0; j < 6; ++j) {
            float s = b[i * 6 + 0] * b[0 * 6 + j];
#pragma unroll
            for (int k = 1; k < 6; ++k)
                s = fmaf(b[i * 6 + k], b[k * 6 + j], s);
            a[i * 6 + j] = s;
        }
}

__global__ __launch_bounds__(256, 2) void matpow4_pipe(
    const float* __restrict__ C, float* __restrict__ out, int nchunk, int B)
{
    __shared__ float4 lds4[2][MPB * 9];   // 73728 B

    const int tid = threadIdx.x;
    const int bid = blockIdx.x;

    const float4* __restrict__ srcAll = reinterpret_cast<const float4*>(C);
    float4* __restrict__ dstAll = reinterpret_cast<float4*>(out);

    // chunks handled by this block: c = bid + t*NB, c < nchunk
    const int n = (bid < nchunk) ? (nchunk - bid + NB - 1) / NB : 0;

    if (n > 0) {
        // prologue: stage chunk 0 into buf 0
        {
            const float4* src = srcAll + (size_t)bid * MPB * 9;
#pragma unroll
            for (int k = 0; k < 9; ++k) {
                int f = k * MPB + tid;
                __builtin_amdgcn_global_load_lds(
                    (const GLOBAL_AS void*)(src + f),
                    (LDS_AS void*)(&lds4[0][f]), 16, 0, 0);
            }
        }

        for (int t = 0; t < n; ++t) {
            const int cur = t & 1;
            const bool pf = (t + 1 < n);

            if (pf) {  // prefetch chunk t+1 into the other buffer
                const int c = bid + (t + 1) * NB;
                const float4* src = srcAll + (size_t)c * MPB * 9;
#pragma unroll
                for (int k = 0; k < 9; ++k) {
                    int f = k * MPB + tid;
                    __builtin_amdgcn_global_load_lds(
                        (const GLOBAL_AS void*)(src + f),
                        (LDS_AS void*)(&lds4[cur ^ 1][f]), 16, 0, 0);
                }
            }

            // wait for chunk t's loads only (prefetch + prev stores may stay
            // in flight); all-full-chunk invariant keeps these counts exact.
            if (t == 0) {
                if (pf) { WAITV9(); } else { WAITV0(); }
            } else if (pf) {
                WAITV18();
            } else {
                WAITV9();
            }
            BAR();

            // compute: own matrix = 9 consecutive float4 (stride-36-word,
            // conflict-free b128 pattern)
            {
                float a[36];
#pragma unroll
                for (int j = 0; j < 9; ++j) {
                    float4 v = lds4[cur][tid * 9 + j];
                    a[4 * j + 0] = v.x;
                    a[4 * j + 1] = v.y;
                    a[4 * j + 2] = v.z;
                    a[4 * j + 3] = v.w;
                }
                pow4_regs(a);
#pragma unroll
                for (int j = 0; j < 9; ++j) {
                    float4 v;
                    v.x = a[4 * j + 0];
                    v.y = a[4 * j + 1];
                    v.z = a[4 * j + 2];
                    v.w = a[4 * j + 3];
                    lds4[cur][tid * 9 + j] = v;
                }
            }
            WAITL();   // ds_writes visible
            BAR();

            // coalesced gather + store of chunk t
            {
                const int c = bid + t * NB;
                float4* dst = dstAll + (size_t)c * MPB * 9;
#pragma unroll
                for (int k = 0; k < 9; ++k) {
                    int f = k * MPB + tid;
                    dst[f] = lds4[cur][f];
                }
            }
            WAITL();   // gather reads complete before buf can be re-staged
            BAR();
        }
    }

    // epilogue: remainder matrices (B % MPB), register-direct, block 0 only.
    if (bid == 0) {
        int idx = nchunk * MPB + tid;
        if (idx < B) {
            const float4* src = srcAll + (size_t)idx * 9;
            float a[36];
#pragma unroll
            for (int j = 0; j < 9; ++j) {
                float4 v = src[j];
                a[4 * j + 0] = v.x;
                a[4 * j + 1] = v.y;
                a[4 * j + 2] = v.z;
                a[4 * j + 3] = v.w;
            }
            pow4_regs(a);
            float4* dst = dstAll + (size_t)idx * 9;
#pragma unroll
            for (int j = 0; j < 9; ++j) {
                float4 v;
                v.x = a[4 * j + 0];
                v.y = a[4 * j + 1];
                v.z = a[4 * j + 2];
                v.w = a[4 * j + 3];
                dst[j] = v;
            }
        }
    }
}

extern "C" void kernel_launch(void* const* d_in, const int* in_sizes, int n_in,
                              void* d_out, int out_size, void* d_ws, size_t ws_size,
                              hipStream_t stream)
{
    const float* C = (const float*)d_in[0];
    float* out = (float*)d_out;
    int B = in_sizes[0] / 36;

    int nchunk = B / MPB;   // full chunks only; remainder via block-0 epilogue
    matpow4_pipe<<<NB, MPB, 0, stream>>>(C, out, nchunk, B);
}

// Round 5
// 109.948 us; speedup vs baseline: 1.0173x; 1.0173x over previous
//
#include <hip/hip_runtime.h>

// C^4 for B independent 6x6 fp32 matrices — persistent single-buffer version.
// 1024 blocks (exactly 4 resident/CU at 36 KB LDS, 16 waves/CU), each loops
// over ~8 full 256-matrix chunks. Per chunk:
//   STAGE (9x global_load_lds w=16, nt) -> __syncthreads (vmcnt0: drains these
//   loads AND the previous chunk's stores in one exposed wait)
//   -> compute C^4 in regs (ds_read_b128/ds_write_b128, conflict-free:
//      matrix = 9 contiguous float4, odd stride) -> __syncthreads
//   -> coalesced gather + nontemporal float4 stores
//   -> raw lgkmcnt(0)+s_barrier (stores stay in flight across the barrier;
//      they drain together with the next stage at the next __syncthreads).
// Remainder (B % 256 = 128 matrices) done register-direct by the last block.

#define MPB 256   // matrices per chunk (= threads per block)
#define NB  1024  // persistent blocks = 4 per CU

#define GLOBAL_AS __attribute__((address_space(1)))
#define LDS_AS    __attribute__((address_space(3)))

typedef float f32x4 __attribute__((ext_vector_type(4)));

__device__ __forceinline__ void pow4_regs(float a[36])
{
    float b[36];
#pragma unroll
    for (int i = 0; i < 6; ++i)
#pragma unroll
        for (int j = 0; j < 6; ++j) {
            float s = a[i * 6 + 0] * a[0 * 6 + j];
#pragma unroll
            for (int k = 1; k < 6; ++k)
                s = fmaf(a[i * 6 + k], a[k * 6 + j], s);
            b[i * 6 + j] = s;
        }
#pragma unroll
    for (int i = 0; i < 6; ++i)
#pragma unroll
        for (int j = 0; j < 6; ++j) {
            float s = b[i * 6 + 0] * b[0 * 6 + j];
#pragma unroll
            for (int k = 1; k < 6; ++k)
                s = fmaf(b[i * 6 + k], b[k * 6 + j], s);
            a[i * 6 + j] = s;
        }
}

__global__ __launch_bounds__(256, 4) void matpow4_persist(
    const float* __restrict__ C, float* __restrict__ out, int nchunk, int B)
{
    __shared__ f32x4 lds4[MPB * 9];   // 36864 B

    const int tid = threadIdx.x;
    const int bid = blockIdx.x;

    const f32x4* __restrict__ srcAll = reinterpret_cast<const f32x4*>(C);
    f32x4* __restrict__ dstAll = reinterpret_cast<f32x4*>(out);

    for (int c = bid; c < nchunk; c += NB) {
        const f32x4* src = srcAll + (size_t)c * (MPB * 9);

        // STAGE: async global -> LDS, linear, coalesced, nt cache policy
#pragma unroll
        for (int k = 0; k < 9; ++k) {
            int f = k * MPB + tid;
            __builtin_amdgcn_global_load_lds(
                (const GLOBAL_AS void*)(src + f),
                (LDS_AS void*)(&lds4[f]), 16, 0, /*aux=nt*/ 2);
        }
        __syncthreads();   // vmcnt(0): drains stage loads + prev-chunk stores

        // COMPUTE: own matrix = 9 consecutive float4 at lds4[tid*9]
        {
            float a[36];
#pragma unroll
            for (int j = 0; j < 9; ++j) {
                f32x4 v = lds4[tid * 9 + j];
                a[4 * j + 0] = v.x;
                a[4 * j + 1] = v.y;
                a[4 * j + 2] = v.z;
                a[4 * j + 3] = v.w;
            }
            pow4_regs(a);
#pragma unroll
            for (int j = 0; j < 9; ++j) {
                f32x4 v;
                v.x = a[4 * j + 0];
                v.y = a[4 * j + 1];
                v.z = a[4 * j + 2];
                v.w = a[4 * j + 3];
                lds4[tid * 9 + j] = v;
            }
        }
        __syncthreads();   // lgkm only in effect (no vmem issued since last)

        // STORE: dense gather + coalesced nontemporal stores
#pragma unroll
        for (int k = 0; k < 9; ++k) {
            int f = k * MPB + tid;
            f32x4 v = lds4[f];
            __builtin_nontemporal_store(v, dstAll + (size_t)c * (MPB * 9) + f);
        }

        // buffer-reuse barrier: gather reads must be done, but let the global
        // stores stay in flight across it (drained at next chunk's sync).
        asm volatile("s_waitcnt lgkmcnt(0)" ::: "memory");
        asm volatile("s_barrier" ::: "memory");
    }

    // remainder matrices (B % MPB), register-direct, last block only
    if (bid == NB - 1) {
        int idx = nchunk * MPB + tid;
        if (idx < B) {
            const f32x4* src = srcAll + (size_t)idx * 9;
            float a[36];
#pragma unroll
            for (int j = 0; j < 9; ++j) {
                f32x4 v = src[j];
                a[4 * j + 0] = v.x;
                a[4 * j + 1] = v.y;
                a[4 * j + 2] = v.z;
                a[4 * j + 3] = v.w;
            }
            pow4_regs(a);
            f32x4* dst = dstAll + (size_t)idx * 9;
#pragma unroll
            for (int j = 0; j < 9; ++j) {
                f32x4 v;
                v.x = a[4 * j + 0];
                v.y = a[4 * j + 1];
                v.z = a[4 * j + 2];
                v.w = a[4 * j + 3];
                dst[j] = v;
            }
        }
    }
}

extern "C" void kernel_launch(void* const* d_in, const int* in_sizes, int n_in,
                              void* d_out, int out_size, void* d_ws, size_t ws_size,
                              hipStream_t stream)
{
    const float* C = (const float*)d_in[0];
    float* out = (float*)d_out;
    int B = in_sizes[0] / 36;

    int nchunk = B / MPB;   // full chunks; remainder via last block
    matpow4_persist<<<NB, MPB, 0, stream>>>(C, out, nchunk, B);
}